// Round 14
// baseline (1245.046 us; speedup 1.0000x reference)
//
#include <hip/hip_runtime.h>

// Problem constants (DecoderLSTMAttn): B=256, L=24, R=49, F=2048, E=256, H=512, A=512, V=10000
constexpr int Bc = 256, Lc = 24, Rc = 49, Fc = 2048, Ec = 256, Hc = 512, Acn = 512, Vc = 10000;
constexpr int STEPS = Lc - 1;           // 23
constexpr int XE = Ec + Fc;             // 2304: W_ih K-dim = [emb | ctx]
constexpr int NG = 2048 + Acn;          // 2560: hgemm out = [gate-contrib | hp]
constexpr int VPAD = 10112;             // V padded to 79*128 for EmbProj GEMM

using bf16x8  = __attribute__((ext_vector_type(8))) __bf16;
using floatx4 = __attribute__((ext_vector_type(4))) float;
using ushort8 = __attribute__((ext_vector_type(8))) unsigned short;
using ushort4v = __attribute__((ext_vector_type(4))) unsigned short;
using ushort2v = __attribute__((ext_vector_type(2))) unsigned short;

__device__ inline float bf2f(unsigned short u) {
    unsigned int x = ((unsigned int)u) << 16;
    float f; __builtin_memcpy(&f, &x, sizeof(f)); return f;
}
__device__ inline unsigned short f2bf(float f) {
    unsigned int u; __builtin_memcpy(&u, &f, sizeof(u));
    u += 0x7fffu + ((u >> 16) & 1u);
    return (unsigned short)(u >> 16);
}

// async global->LDS 16B (linear dest: wave-uniform base + lane*16)
__device__ inline void gload_lds16(const void* g, void* l) {
    __builtin_amdgcn_global_load_lds(
        (const __attribute__((address_space(1))) unsigned int*)g,
        (__attribute__((address_space(3))) unsigned int*)l, 16, 0, 0);
}

// ---------------------------------------------------------------------------
// One-shot fp32->bf16 convert of all 9 tensors (constexpr segment table).
// ---------------------------------------------------------------------------
struct CvtArgs {
    const float* src[9];
    unsigned short* dst[9];
};
constexpr int SEG_END[9] = {
    6422528,   // feats   256*49*2048/4
    7062528,   // embW    +10000*256/4
    7324672,   // Wf      +512*2048/4
    8604672,   // Wfc     +10000*512/4
    9784320,   // W_ih    +2048*2304/4
    10046464,  // W_hh    +2048*512/4   (-> Whg rows 0..2047)
    10112000,  // Wh      +512*512/4    (-> Whg rows 2048..2559)
    10374144,  // Wi_h    +512*2048/4
    10636288   // Wi_c    +512*2048/4
};
constexpr int CVT_BLOCKS = SEG_END[8] / 256;  // exact

__global__ __launch_bounds__(256) void convert_all(CvtArgs a)
{
    int g = blockIdx.x * 256 + threadIdx.x;
    int s = 0, base = 0;
    #pragma unroll
    for (int i = 0; i < 9; i++)
        if (g >= SEG_END[i]) { s = i + 1; }
    if (s >= 9) return;
    base = (s == 0) ? 0 : SEG_END[s - 1];
    const float* sp = a.src[s];
    unsigned short* dp = a.dst[s];
    int off = g - base;
    float4 v = reinterpret_cast<const float4*>(sp)[off];
    ushort4v o;
    o.x = f2bf(v.x); o.y = f2bf(v.y); o.z = f2bf(v.z); o.w = f2bf(v.w);
    reinterpret_cast<ushort4v*>(dp)[off] = o;
}

// ---------------------------------------------------------------------------
// Generic TN GEMM (bf16 in, fp32 acc, MFMA 16x16x32), BK=64.
// global_load_lds 16B staging into linear LDS, content XOR-swizzled via
// pre-swizzled global source (involution on 16B blocks within 128B rows).
// SWAP: m from blockIdx.y, n from blockIdx.x. With x-fastest dispatch, the
//       n-tiles of one m-tile become consecutive/concurrent -> each A-panel
//       is HBM-fetched once (round-13: m-fastest order re-fetched A 6x,
//       FETCH 351 MB vs 60 MB unique on FprojG).
// NOTE: XCD-chunked remap on these grids REVERTED (round-10: 8x A-dup).
// lens/tcur (EPI 0 only): skip m-tiles whose rows are all inactive at step
//       tcur (lengths sorted desc; rows are batch indices).
// EPI 0: outF fp32 = acc (+bias if non-null)           (hgemm)
// EPI 1: outU bf16 = acc (+bias if non-null)           (f_proj / FprojG / EmbProj)
// EPI 2: h0/c0: B/bias select by n<512; tanh; n<512 -> h_buf bf16,
//        else c_state fp32                             (h0c0)
// ---------------------------------------------------------------------------
template <int BM, int BN, int BK, int EPI, bool SWAP = false>
__global__ __launch_bounds__(256) void gemm_tn(
    const unsigned short* __restrict__ A, int lda,
    const unsigned short* __restrict__ Bm, int ldb,
    const unsigned short* __restrict__ Bm2,
    const float* __restrict__ bias,
    const float* __restrict__ bias2,
    float* __restrict__ outF,
    unsigned short* __restrict__ outU,
    float* __restrict__ outF2,
    int N, int K,
    const int* __restrict__ lens, int tcur)
{
    static_assert(BK == 64, "row must be 128B for the swizzle");
    __shared__ __align__(16) unsigned short smem[(BM + BN) * BK];
    unsigned short* sA = smem;
    unsigned short* sB = smem + BM * BK;

    const int tid = threadIdx.x;
    const int wid = tid >> 6, lane = tid & 63;
    const int wm = wid >> 1, wn = wid & 1;
    const int m0 = (SWAP ? blockIdx.y : blockIdx.x) * BM;
    const int n0 = (SWAP ? blockIdx.x : blockIdx.y) * BN;

    if constexpr (EPI == 0) {
        // ragged skip: rows are batch indices, lengths sorted desc
        if (lens && lens[m0] <= tcur) return;
    }

    constexpr int FM = BM / 32, FN = (BN + 31) / 32;
    constexpr int ACH = BM / 32;   // 1KB chunks per wave for A
    constexpr int BCH = BN / 32;   // 1KB chunks per wave for B

    floatx4 acc[FM][FN];
    #pragma unroll
    for (int i = 0; i < FM; i++)
        #pragma unroll
        for (int j = 0; j < FN; j++)
            #pragma unroll
            for (int r = 0; r < 4; r++) acc[i][j][r] = 0.f;

    const int lm = lane & 15, half = lane >> 4;
    const int lane16 = lane * 16;

    for (int k0 = 0; k0 < K; k0 += BK) {
        #pragma unroll
        for (int ii = 0; ii < ACH; ii++) {
            int ldso = (wid * ACH + ii) * 1024 + lane16;
            int row = ldso >> 7, colb = ldso & 127;
            int scolb = colb ^ ((row & 7) << 4);
            const char* src = (const char*)(A + (size_t)(m0 + row) * lda + k0) + scolb;
            gload_lds16(src, (char*)sA + ldso);
        }
        #pragma unroll
        for (int ii = 0; ii < BCH; ii++) {
            int ldso = (wid * BCH + ii) * 1024 + lane16;
            int row = ldso >> 7, colb = ldso & 127;
            int scolb = colb ^ ((row & 7) << 4);
            int gn = n0 + row;
            const unsigned short* bp;
            if constexpr (EPI == 2)
                bp = (gn < Hc) ? (Bm + (size_t)gn * ldb) : (Bm2 + (size_t)(gn - Hc) * ldb);
            else
                bp = Bm + (size_t)gn * ldb;
            gload_lds16((const char*)(bp + k0) + scolb, (char*)sB + ldso);
        }
        __syncthreads();   // drains vmcnt(0): staged data visible

        #pragma unroll
        for (int kk = 0; kk < BK; kk += 32) {
            bf16x8 af[FM], bfb[FN];
            #pragma unroll
            for (int fm = 0; fm < FM; fm++) {
                int ar = wm * (BM / 2) + fm * 16 + lm;
                int ab = ar * 128 + ((kk * 2 + half * 16) ^ ((ar & 7) << 4));
                af[fm] = *reinterpret_cast<const bf16x8*>((const char*)sA + ab);
            }
            #pragma unroll
            for (int fn = 0; fn < FN; fn++) {
                int br = wn * (BN / 2) + fn * 16 + lm;
                int bb = br * 128 + ((kk * 2 + half * 16) ^ ((br & 7) << 4));
                bfb[fn] = *reinterpret_cast<const bf16x8*>((const char*)sB + bb);
            }
            #pragma unroll
            for (int fm = 0; fm < FM; fm++)
                #pragma unroll
                for (int fn = 0; fn < FN; fn++)
                    acc[fm][fn] = __builtin_amdgcn_mfma_f32_16x16x32_bf16(
                        af[fm], bfb[fn], acc[fm][fn], 0, 0, 0);
        }
        __syncthreads();
    }

    const int quad = lane >> 4;
    #pragma unroll
    for (int fm = 0; fm < FM; fm++) {
        #pragma unroll
        for (int fn = 0; fn < FN; fn++) {
            #pragma unroll
            for (int r = 0; r < 4; r++) {
                int rowG = m0 + wm * (BM / 2) + fm * 16 + quad * 4 + r;
                int colG = n0 + wn * (BN / 2) + fn * 16 + lm;
                float v = acc[fm][fn][r];
                if constexpr (EPI == 0) {
                    if (bias) v += bias[colG];
                    outF[(size_t)rowG * N + colG] = v;
                } else if constexpr (EPI == 1) {
                    if (bias) v += bias[colG];
                    outU[(size_t)rowG * N + colG] = f2bf(v);
                } else if constexpr (EPI == 2) {
                    float b = (colG < Hc) ? bias[colG] : bias2[colG - Hc];
                    v = tanhf(v + b);
                    if (colG < Hc) outU[(size_t)rowG * Hc + colG] = f2bf(v);
                    else           outF2[(size_t)rowG * Hc + (colG - Hc)] = v;
                }
            }
        }
    }
}

// ---------------------------------------------------------------------------
// Batched logits GEMM: out[(b*STEPS+t)*V+n] = h_all[t*256+b,:] . Wfc[n,:] + bfc[n]
// (zeroed where lengths[b] <= t). BM=128, BN=64, BK=64.
// - XCD-chunked bijective swizzle (kept: measured-good here -- n-panel reuse
//   dominates since A=h_all is tiny); coalesced 256B epilogue; tile skip.
// - h_all rows of inactive (t,b) are garbage (attn skipped) -- safe: GEMM
//   output rows are per-A-row isolated and masked to 0 at store.
// ---------------------------------------------------------------------------
__global__ __launch_bounds__(256) void logits_gemm(
    const unsigned short* __restrict__ A,   // h_all [5888][512]
    const unsigned short* __restrict__ Bm,  // WfcB [10000][512] (+overrun ok)
    const float* __restrict__ bias,         // bfc
    float* __restrict__ out,
    const int* __restrict__ lengths)
{
    constexpr int BM = 128, BN = 64, BK = 64, K = Hc;
    constexpr int EP = 68;  // epilogue fp32 row stride
    __shared__ __align__(16) unsigned char smraw[BM * EP * 4];  // 34816 B
    unsigned short* sA = (unsigned short*)smraw;                // [128][64] linear
    unsigned short* sB = sA + BM * BK;                          // [64][64] linear
    float* sE = (float*)smraw;

    const int tid = threadIdx.x;
    const int wid = tid >> 6, lane = tid & 63;
    const int wm = wid >> 1, wn = wid & 1;

    // bijective XCD-chunked remap (8 XCDs, grid 46 x 157 = 7222)
    constexpr int NWG = 46 * 157, NX = 8;
    constexpr int qq = NWG / NX, rr = NWG % NX;   // 902, 6
    int wg = blockIdx.x + blockIdx.y * 46;
    int xcd = wg % NX, i = wg / NX;
    int w = (xcd < rr ? xcd * (qq + 1) : rr * (qq + 1) + (xcd - rr) * qq) + i;
    const int m0 = (w % 46) * BM, n0 = (w / 46) * BN;
    constexpr int FM = 4, FN = 2;

    const int rl = lane >> 4, cl = lane & 15;
    const int colG = n0 + cl * 4;
    const bool colOK = colG < Vc;   // Vc%4==0 -> float4 fully in or out

    // ---- inactive-tile fast path ----
    const int tt0 = m0 >> 8;
    if (lengths[m0 & 255] <= tt0) {
        if (colOK) {
            float4 z; z.x = 0.f; z.y = 0.f; z.z = 0.f; z.w = 0.f;
            #pragma unroll
            for (int it = 0; it < 8; it++) {
                int r = wid * 32 + it * 4 + rl;
                int bb = (m0 + r) & 255;
                *reinterpret_cast<float4*>(
                    out + ((size_t)bb * STEPS + tt0) * Vc + colG) = z;
            }
        }
        return;
    }

    floatx4 acc[FM][FN];
    #pragma unroll
    for (int i2 = 0; i2 < FM; i2++)
        #pragma unroll
        for (int j = 0; j < FN; j++)
            #pragma unroll
            for (int r = 0; r < 4; r++) acc[i2][j][r] = 0.f;

    const int lm = lane & 15, half = lane >> 4;
    const int lane16 = lane * 16;

    for (int k0 = 0; k0 < K; k0 += BK) {
        #pragma unroll
        for (int ii = 0; ii < 4; ii++) {           // A: 16 x 1KB chunks
            int ldso = (wid * 4 + ii) * 1024 + lane16;
            int row = ldso >> 7, colb = ldso & 127;
            int scolb = colb ^ ((row & 7) << 4);
            const char* src = (const char*)(A + (size_t)(m0 + row) * K + k0) + scolb;
            gload_lds16(src, (char*)sA + ldso);
        }
        #pragma unroll
        for (int ii = 0; ii < 2; ii++) {           // B: 8 x 1KB chunks
            int ldso = (wid * 2 + ii) * 1024 + lane16;
            int row = ldso >> 7, colb = ldso & 127;
            int scolb = colb ^ ((row & 7) << 4);
            const char* src = (const char*)(Bm + (size_t)(n0 + row) * K + k0) + scolb;
            gload_lds16(src, (char*)sB + ldso);
        }
        __syncthreads();

        #pragma unroll
        for (int kk = 0; kk < BK; kk += 32) {
            bf16x8 af[FM], bfb[FN];
            #pragma unroll
            for (int fm = 0; fm < FM; fm++) {
                int ar = wm * 64 + fm * 16 + lm;
                int ab = ar * 128 + ((kk * 2 + half * 16) ^ ((ar & 7) << 4));
                af[fm] = *reinterpret_cast<const bf16x8*>((const char*)sA + ab);
            }
            #pragma unroll
            for (int fn = 0; fn < FN; fn++) {
                int br = wn * 32 + fn * 16 + lm;
                int bb = br * 128 + ((kk * 2 + half * 16) ^ ((br & 7) << 4));
                bfb[fn] = *reinterpret_cast<const bf16x8*>((const char*)sB + bb);
            }
            #pragma unroll
            for (int fm = 0; fm < FM; fm++)
                #pragma unroll
                for (int fn = 0; fn < FN; fn++)
                    acc[fm][fn] = __builtin_amdgcn_mfma_f32_16x16x32_bf16(
                        af[fm], bfb[fn], acc[fm][fn], 0, 0, 0);
        }
        __syncthreads();
    }

    // dump acc to LDS fp32 (C-layout)
    const int quad = lane >> 4;
    #pragma unroll
    for (int fm = 0; fm < FM; fm++)
        #pragma unroll
        for (int fn = 0; fn < FN; fn++)
            #pragma unroll
            for (int r = 0; r < 4; r++)
                sE[(wm * 64 + fm * 16 + quad * 4 + r) * EP + wn * 32 + fn * 16 + lm]
                    = acc[fm][fn][r];
    __syncthreads();

    // coalesced epilogue: 16 lanes cover a full 256B row segment per instr
    if (colOK) {
        float4 bv = *reinterpret_cast<const float4*>(bias + colG);
        #pragma unroll
        for (int it = 0; it < 8; it++) {
            int r = wid * 32 + it * 4 + rl;
            int rowG = m0 + r;
            int tt = rowG >> 8, bb = rowG & 255;
            bool act = lengths[bb] > tt;
            float4 v = *reinterpret_cast<const float4*>(sE + r * EP + cl * 4);
            float4 o;
            o.x = act ? v.x + bv.x : 0.f;
            o.y = act ? v.y + bv.y : 0.f;
            o.z = act ? v.z + bv.z : 0.f;
            o.w = act ? v.w + bv.w : 0.f;
            *reinterpret_cast<float4*>(out + ((size_t)bb * STEPS + tt) * Vc + colG) = o;
        }
    }
}

// ---------------------------------------------------------------------------
// Fused attention + gate-sum + LSTM pointwise. One block per batch row b.
// 1024 threads (16 waves/CU) -- latency-bound loop, confirmed rounds 12-13.
// RAGGED SKIP: inactive rows exit immediately.
// ---------------------------------------------------------------------------
__global__ __launch_bounds__(1024) void attn_lstm_kernel(
    const unsigned short* __restrict__ fproj,    // [256][49][512] bf16
    const unsigned short* __restrict__ fprojG,   // [256][49][2048] bf16
    const unsigned short* __restrict__ embProj,  // [10112][2048] bf16
    const float* __restrict__ hg,                // [256][2560]
    const float* __restrict__ bh,
    const float* __restrict__ Ws,
    const float* __restrict__ bs,
    const float* __restrict__ b_ih,
    const float* __restrict__ b_hh,
    float* __restrict__ c_state,
    unsigned short* __restrict__ h_buf,
    unsigned short* __restrict__ h_all,
    const int* __restrict__ lengths,
    const int* __restrict__ ids,
    int t)
{
    const int b = blockIdx.x, tid = threadIdx.x;
    if (lengths[b] <= t) return;   // ragged skip: h,c preserved; logits masked

    const int wid = tid >> 6, lane = tid & 63;
    __shared__ float s_hp[Acn];
    __shared__ float s_sc[64];
    __shared__ float s_g[2048];

    if (tid < Acn)
        s_hp[tid] = hg[(size_t)b * NG + 2048 + tid] + bh[tid];
    __syncthreads();

    // --- scores: 49 rows over 16 waves (<=4 iters) ---
    float ws8[8], hp8[8];
    {
        const float* wsb = Ws + lane * 8;
        #pragma unroll
        for (int j = 0; j < 8; j++) { ws8[j] = wsb[j]; hp8[j] = s_hp[lane * 8 + j]; }
    }
    for (int r = wid; r < Rc; r += 16) {
        ushort8 e = *reinterpret_cast<const ushort8*>(
            fproj + ((size_t)b * Rc + r) * Acn + lane * 8);
        float sum = 0.f;
        #pragma unroll
        for (int j = 0; j < 8; j++)
            sum += ws8[j] * tanhf(bf2f(e[j]) + hp8[j]);
        #pragma unroll
        for (int off = 32; off > 0; off >>= 1) sum += __shfl_down(sum, off);
        if (lane == 0) s_sc[r] = sum + bs[0];
    }
    __syncthreads();

    // --- softmax over R=49 (wave 0) ---
    if (wid == 0) {
        float v = (lane < Rc) ? s_sc[lane] : -3.0e38f;
        float mx = v;
        #pragma unroll
        for (int off = 32; off > 0; off >>= 1) mx = fmaxf(mx, __shfl_xor(mx, off));
        float e = (lane < Rc) ? __expf(v - mx) : 0.f;
        float sm = e;
        #pragma unroll
        for (int off = 32; off > 0; off >>= 1) sm += __shfl_xor(sm, off);
        if (lane < Rc) s_sc[lane] = e / sm;
    }
    __syncthreads();

    // --- gates: EmbProj[id] + alpha . FprojG + hg + biases (2 per thread) ---
    const int g0 = tid * 2;
    const int id = ids[b * Lc + t];
    float g2[2];
    {
        ushort2v ev = *reinterpret_cast<const ushort2v*>(embProj + (size_t)id * 2048 + g0);
        const float* hgb = hg + (size_t)b * NG + g0;
        #pragma unroll
        for (int j = 0; j < 2; j++)
            g2[j] = bf2f(ev[j]) + hgb[j] + b_ih[g0 + j] + b_hh[g0 + j];
    }
    #pragma unroll 7
    for (int r = 0; r < Rc; r++) {
        float a = s_sc[r];
        ushort2v v = *reinterpret_cast<const ushort2v*>(
            fprojG + ((size_t)b * Rc + r) * 2048 + g0);
        #pragma unroll
        for (int j = 0; j < 2; j++) g2[j] += a * bf2f(v[j]);
    }
    #pragma unroll
    for (int j = 0; j < 2; j++) s_g[g0 + j] = g2[j];
    __syncthreads();

    // --- LSTM pointwise: 1 hidden unit per thread (tid < 512) ---
    if (tid < Hc) {
        int j = tid;
        float gi = s_g[j], gf = s_g[Hc + j], gg = s_g[2 * Hc + j], go = s_g[3 * Hc + j];
        float i_ = 1.f / (1.f + __expf(-gi));
        float f_ = 1.f / (1.f + __expf(-gf));
        float gv = tanhf(gg);
        float o_ = 1.f / (1.f + __expf(-go));
        float c_old = c_state[(size_t)b * Hc + j];
        float ct = f_ * c_old + i_ * gv;
        float ht = o_ * tanhf(ct);
        unsigned short hb = f2bf(ht);
        h_all[((size_t)t * Bc + b) * Hc + j] = hb;
        c_state[(size_t)b * Hc + j] = ct;
        h_buf[(size_t)b * Hc + j] = hb;
    }
}

// ---------------------------------------------------------------------------
// Setup: mean over R of featsB.
// ---------------------------------------------------------------------------
__global__ __launch_bounds__(256) void mean_kernel(
    const unsigned short* __restrict__ featsB,
    unsigned short* __restrict__ meanB)
{
    const int b = blockIdx.x, tid = threadIdx.x;
    const int f0 = tid * 8;
    float s[8];
    #pragma unroll
    for (int j = 0; j < 8; j++) s[j] = 0.f;
    #pragma unroll 7
    for (int r = 0; r < Rc; r++) {
        ushort8 v = *reinterpret_cast<const ushort8*>(
            featsB + ((size_t)(b * Rc + r)) * Fc + f0);
        #pragma unroll
        for (int j = 0; j < 8; j++) s[j] += bf2f(v[j]);
    }
    ushort8 o;
    #pragma unroll
    for (int j = 0; j < 8; j++) o[j] = f2bf(s[j] * (1.f / (float)Rc));
    *reinterpret_cast<ushort8*>(meanB + (size_t)b * Fc + f0) = o;
}

// ---------------------------------------------------------------------------
extern "C" void kernel_launch(void* const* d_in, const int* in_sizes, int n_in,
                              void* d_out, int out_size, void* d_ws, size_t ws_size,
                              hipStream_t stream)
{
    const float* feats = (const float*)d_in[0];
    const int*   ids   = (const int*)d_in[1];
    const int*   lens  = (const int*)d_in[2];
    const float* embW  = (const float*)d_in[3];
    const float* Wf    = (const float*)d_in[4];
    const float* bf_   = (const float*)d_in[5];
    const float* Wh    = (const float*)d_in[6];
    const float* bh    = (const float*)d_in[7];
    const float* Ws_   = (const float*)d_in[8];
    const float* bs_   = (const float*)d_in[9];
    const float* W_ih  = (const float*)d_in[10];
    const float* b_ih  = (const float*)d_in[11];
    const float* W_hh  = (const float*)d_in[12];
    const float* b_hh  = (const float*)d_in[13];
    const float* Wfc   = (const float*)d_in[14];
    const float* bfc   = (const float*)d_in[15];
    const float* Wi_h  = (const float*)d_in[16];
    const float* bi_h  = (const float*)d_in[17];
    const float* Wi_c  = (const float*)d_in[18];
    const float* bi_c  = (const float*)d_in[19];

    char* ws = (char*)d_ws;
    auto alloc_us = [&](size_t n) { unsigned short* p = (unsigned short*)ws; ws += n * 2; return p; };
    auto alloc_f  = [&](size_t n) { float* p = (float*)ws; ws += n * 4; return p; };

    unsigned short* featsB = alloc_us((size_t)Bc * Rc * Fc);
    unsigned short* embB   = alloc_us((size_t)Vc * Ec);
    unsigned short* WfB    = alloc_us((size_t)Acn * Fc);
    unsigned short* WfcB   = alloc_us((size_t)Vc * Hc);
    unsigned short* WihB   = alloc_us((size_t)2048 * XE);
    unsigned short* Whg    = alloc_us((size_t)NG * Hc);   // [W_hh ; Wh]
    unsigned short* WihB2  = alloc_us((size_t)Hc * Fc);   // Wi_h
    unsigned short* WicB   = alloc_us((size_t)Hc * Fc);   // Wi_c
    unsigned short* meanB  = alloc_us((size_t)Bc * Fc);
    unsigned short* fproj  = alloc_us((size_t)Bc * Rc * Acn);
    unsigned short* fprojG = alloc_us((size_t)Bc * Rc * 2048);   // feats @ W_ctx^T
    unsigned short* embPrj = alloc_us((size_t)VPAD * 2048);      // embW @ W_emb^T (padded rows)
    unsigned short* h_buf  = alloc_us((size_t)Bc * Hc);
    unsigned short* h_all  = alloc_us((size_t)STEPS * Bc * Hc);
    float*          c_st   = alloc_f((size_t)Bc * Hc);
    float*          hg     = alloc_f((size_t)Bc * NG);
    float*          outF   = (float*)d_out;

    CvtArgs ca;
    ca.src[0] = feats; ca.dst[0] = featsB;
    ca.src[1] = embW;  ca.dst[1] = embB;
    ca.src[2] = Wf;    ca.dst[2] = WfB;
    ca.src[3] = Wfc;   ca.dst[3] = WfcB;
    ca.src[4] = W_ih;  ca.dst[4] = WihB;
    ca.src[5] = W_hh;  ca.dst[5] = Whg;                       // rows 0..2047
    ca.src[6] = Wh;    ca.dst[6] = Whg + (size_t)2048 * Hc;   // rows 2048..2559
    ca.src[7] = Wi_h;  ca.dst[7] = WihB2;
    ca.src[8] = Wi_c;  ca.dst[8] = WicB;
    convert_all<<<CVT_BLOCKS, 256, 0, stream>>>(ca);

    mean_kernel<<<Bc, 256, 0, stream>>>(featsB, meanB);

    // h0/c0 init: M=256, N=1024 (Wi_h|Wi_c), K=2048, tanh epilogue
    gemm_tn<64, 64, 64, 2><<<dim3(4, 16), 256, 0, stream>>>(
        meanB, Fc, WihB2, Fc, WicB, bi_h, bi_c,
        nullptr, h_buf, c_st, 2 * Hc, Fc, nullptr, 0);

    // f_proj: M=12544, N=512, K=2048 -> bf16 (n-fastest dispatch: A once)
    gemm_tn<128, 128, 64, 1, true><<<dim3(4, 98), 256, 0, stream>>>(
        featsB, Fc, WfB, Fc, nullptr, bf_, nullptr,
        nullptr, fproj, nullptr, Acn, Fc, nullptr, 0);

    // FprojG = feats @ W_ih[:,256:]^T : M=12544, N=2048, K=2048 -> bf16
    // (n-fastest dispatch: 16 n-tiles of one m-tile run concurrently)
    gemm_tn<128, 128, 64, 1, true><<<dim3(16, 98), 256, 0, stream>>>(
        featsB, Fc, WihB + 256, XE, nullptr, nullptr, nullptr,
        nullptr, fprojG, nullptr, 2048, Fc, nullptr, 0);

    // EmbProj = embW @ W_ih[:,0:256]^T : M=10112 (padded), N=2048, K=256 -> bf16
    gemm_tn<128, 128, 64, 1, true><<<dim3(16, VPAD / 128), 256, 0, stream>>>(
        embB, Ec, WihB, XE, nullptr, nullptr, nullptr,
        nullptr, embPrj, nullptr, 2048, Ec, nullptr, 0);

    for (int t = 0; t < STEPS; t++) {
        // hgemm: hg = h @ [W_hh;Wh]^T : M=256, N=2560, K=512 -> 320 blocks
        // (with ragged m-tile skip: 64-row tiles fully inactive at t exit)
        gemm_tn<64, 32, 64, 0><<<dim3(4, 80), 256, 0, stream>>>(
            h_buf, Hc, Whg, Hc, nullptr, nullptr, nullptr,
            hg, nullptr, nullptr, NG, Hc, lens, t);

        // fused attention + gate-sum + LSTM pointwise (1024 thr, ragged skip)
        attn_lstm_kernel<<<Bc, 1024, 0, stream>>>(
            fproj, fprojG, embPrj, hg, bh, Ws_, bs_, b_ih, b_hh,
            c_st, h_buf, h_all, lens, ids, t);
    }

    // batched logits: M=5888, N=10000, K=512
    logits_gemm<<<dim3(46, 157), 256, 0, stream>>>(
        h_all, WfcB, bfc, outF, lens);
}

// Round 15
// 1201.262 us; speedup vs baseline: 1.0364x; 1.0364x over previous
//
#include <hip/hip_runtime.h>

// Problem constants (DecoderLSTMAttn): B=256, L=24, R=49, F=2048, E=256, H=512, A=512, V=10000
constexpr int Bc = 256, Lc = 24, Rc = 49, Fc = 2048, Ec = 256, Hc = 512, Acn = 512, Vc = 10000;
constexpr int STEPS = Lc - 1;           // 23
constexpr int XE = Ec + Fc;             // 2304: W_ih K-dim = [emb | ctx]
constexpr int NG = 2048 + Acn;          // 2560: hgemm out = [gate-contrib | hp]
constexpr int VPAD = 10112;             // V padded to 79*128 (EmbProj GEMM + logits n-tiling)

using bf16x8  = __attribute__((ext_vector_type(8))) __bf16;
using floatx4 = __attribute__((ext_vector_type(4))) float;
using ushort8 = __attribute__((ext_vector_type(8))) unsigned short;
using ushort4v = __attribute__((ext_vector_type(4))) unsigned short;
using ushort2v = __attribute__((ext_vector_type(2))) unsigned short;

__device__ inline float bf2f(unsigned short u) {
    unsigned int x = ((unsigned int)u) << 16;
    float f; __builtin_memcpy(&f, &x, sizeof(f)); return f;
}
__device__ inline unsigned short f2bf(float f) {
    unsigned int u; __builtin_memcpy(&u, &f, sizeof(u));
    u += 0x7fffu + ((u >> 16) & 1u);
    return (unsigned short)(u >> 16);
}

// async global->LDS 16B (linear dest: wave-uniform base + lane*16)
__device__ inline void gload_lds16(const void* g, void* l) {
    __builtin_amdgcn_global_load_lds(
        (const __attribute__((address_space(1))) unsigned int*)g,
        (__attribute__((address_space(3))) unsigned int*)l, 16, 0, 0);
}

// ---------------------------------------------------------------------------
// One-shot fp32->bf16 convert of all 9 tensors (constexpr segment table).
// ---------------------------------------------------------------------------
struct CvtArgs {
    const float* src[9];
    unsigned short* dst[9];
};
constexpr int SEG_END[9] = {
    6422528,   // feats   256*49*2048/4
    7062528,   // embW    +10000*256/4
    7324672,   // Wf      +512*2048/4
    8604672,   // Wfc     +10000*512/4
    9784320,   // W_ih    +2048*2304/4
    10046464,  // W_hh    +2048*512/4   (-> Whg rows 0..2047)
    10112000,  // Wh      +512*512/4    (-> Whg rows 2048..2559)
    10374144,  // Wi_h    +512*2048/4
    10636288   // Wi_c    +512*2048/4
};
constexpr int CVT_BLOCKS = SEG_END[8] / 256;  // exact

__global__ __launch_bounds__(256) void convert_all(CvtArgs a)
{
    int g = blockIdx.x * 256 + threadIdx.x;
    int s = 0, base = 0;
    #pragma unroll
    for (int i = 0; i < 9; i++)
        if (g >= SEG_END[i]) { s = i + 1; }
    if (s >= 9) return;
    base = (s == 0) ? 0 : SEG_END[s - 1];
    const float* sp = a.src[s];
    unsigned short* dp = a.dst[s];
    int off = g - base;
    float4 v = reinterpret_cast<const float4*>(sp)[off];
    ushort4v o;
    o.x = f2bf(v.x); o.y = f2bf(v.y); o.z = f2bf(v.z); o.w = f2bf(v.w);
    reinterpret_cast<ushort4v*>(dp)[off] = o;
}

// ---------------------------------------------------------------------------
// Generic TN GEMM (bf16 in, fp32 acc, MFMA 16x16x32), variable BK (mult of 64).
// global_load_lds 16B staging into linear LDS, content XOR-swizzled via
// pre-swizzled global source (involution on 16B blocks; stays in-row since
// LRS = BK*2 is a multiple of 128). Bank-free reads: ar*LRS/4 % 32 == 0 and
// XOR spreads 16 rows over 8 banks (2-way = free, m136).
// SWAP: m from blockIdx.y, n from blockIdx.x (n-fastest dispatch: A-panels
//       HBM-fetched once; round-14 measured FETCH 351->217 MB on FprojG).
// lens/tcur (EPI 0 only): ragged m-tile skip.
// EPI 0: outF fp32 (hgemm)  EPI 1: outU bf16  EPI 2: h0/c0 tanh split.
// ---------------------------------------------------------------------------
template <int BM, int BN, int BK, int EPI, bool SWAP = false>
__global__ __launch_bounds__(256) void gemm_tn(
    const unsigned short* __restrict__ A, int lda,
    const unsigned short* __restrict__ Bm, int ldb,
    const unsigned short* __restrict__ Bm2,
    const float* __restrict__ bias,
    const float* __restrict__ bias2,
    float* __restrict__ outF,
    unsigned short* __restrict__ outU,
    float* __restrict__ outF2,
    int N, int K,
    const int* __restrict__ lens, int tcur)
{
    static_assert(BK % 64 == 0, "BK multiple of 64 (row stride multiple of 128B)");
    constexpr int LRS = BK * 2;                      // LDS row stride bytes
    __shared__ __align__(16) unsigned short smem[(BM + BN) * BK];
    unsigned short* sA = smem;
    unsigned short* sB = smem + BM * BK;

    const int tid = threadIdx.x;
    const int wid = tid >> 6, lane = tid & 63;
    const int wm = wid >> 1, wn = wid & 1;
    const int m0 = (SWAP ? blockIdx.y : blockIdx.x) * BM;
    const int n0 = (SWAP ? blockIdx.x : blockIdx.y) * BN;

    if constexpr (EPI == 0) {
        if (lens && lens[m0] <= tcur) return;        // ragged skip
    }

    constexpr int FM = BM / 32, FN = (BN + 31) / 32;
    constexpr int ACH = BM * LRS / 4096;             // 1KB chunks/wave for A
    constexpr int BCH = BN * LRS / 4096;             // 1KB chunks/wave for B

    floatx4 acc[FM][FN];
    #pragma unroll
    for (int i = 0; i < FM; i++)
        #pragma unroll
        for (int j = 0; j < FN; j++)
            #pragma unroll
            for (int r = 0; r < 4; r++) acc[i][j][r] = 0.f;

    const int lm = lane & 15, half = lane >> 4;
    const int lane16 = lane * 16;

    for (int k0 = 0; k0 < K; k0 += BK) {
        #pragma unroll
        for (int ii = 0; ii < ACH; ii++) {
            int ldso = (wid * ACH + ii) * 1024 + lane16;
            int row = ldso / LRS, colb = ldso % LRS;
            int scolb = colb ^ ((row & 7) << 4);
            const char* src = (const char*)(A + (size_t)(m0 + row) * lda + k0) + scolb;
            gload_lds16(src, (char*)sA + ldso);
        }
        #pragma unroll
        for (int ii = 0; ii < BCH; ii++) {
            int ldso = (wid * BCH + ii) * 1024 + lane16;
            int row = ldso / LRS, colb = ldso % LRS;
            int scolb = colb ^ ((row & 7) << 4);
            int gn = n0 + row;
            const unsigned short* bp;
            if constexpr (EPI == 2)
                bp = (gn < Hc) ? (Bm + (size_t)gn * ldb) : (Bm2 + (size_t)(gn - Hc) * ldb);
            else
                bp = Bm + (size_t)gn * ldb;
            gload_lds16((const char*)(bp + k0) + scolb, (char*)sB + ldso);
        }
        __syncthreads();   // drains vmcnt(0): staged data visible

        #pragma unroll
        for (int kk = 0; kk < BK; kk += 32) {
            bf16x8 af[FM], bfb[FN];
            #pragma unroll
            for (int fm = 0; fm < FM; fm++) {
                int ar = wm * (BM / 2) + fm * 16 + lm;
                int ab = ar * LRS + ((kk * 2 + half * 16) ^ ((ar & 7) << 4));
                af[fm] = *reinterpret_cast<const bf16x8*>((const char*)sA + ab);
            }
            #pragma unroll
            for (int fn = 0; fn < FN; fn++) {
                int br = wn * (BN / 2) + fn * 16 + lm;
                int bb = br * LRS + ((kk * 2 + half * 16) ^ ((br & 7) << 4));
                bfb[fn] = *reinterpret_cast<const bf16x8*>((const char*)sB + bb);
            }
            #pragma unroll
            for (int fm = 0; fm < FM; fm++)
                #pragma unroll
                for (int fn = 0; fn < FN; fn++)
                    acc[fm][fn] = __builtin_amdgcn_mfma_f32_16x16x32_bf16(
                        af[fm], bfb[fn], acc[fm][fn], 0, 0, 0);
        }
        __syncthreads();
    }

    const int quad = lane >> 4;
    #pragma unroll
    for (int fm = 0; fm < FM; fm++) {
        #pragma unroll
        for (int fn = 0; fn < FN; fn++) {
            #pragma unroll
            for (int r = 0; r < 4; r++) {
                int rowG = m0 + wm * (BM / 2) + fm * 16 + quad * 4 + r;
                int colG = n0 + wn * (BN / 2) + fn * 16 + lm;
                float v = acc[fm][fn][r];
                if constexpr (EPI == 0) {
                    if (bias) v += bias[colG];
                    outF[(size_t)rowG * N + colG] = v;
                } else if constexpr (EPI == 1) {
                    if (bias) v += bias[colG];
                    outU[(size_t)rowG * N + colG] = f2bf(v);
                } else if constexpr (EPI == 2) {
                    float b = (colG < Hc) ? bias[colG] : bias2[colG - Hc];
                    v = tanhf(v + b);
                    if (colG < Hc) outU[(size_t)rowG * Hc + colG] = f2bf(v);
                    else           outF2[(size_t)rowG * Hc + (colG - Hc)] = v;
                }
            }
        }
    }
}

// ---------------------------------------------------------------------------
// Batched logits GEMM: out[(b*STEPS+t)*V+n] = h_all[t*256+b,:] . Wfc[n,:] + bfc[n]
// (zeroed where lengths[b] <= t). BM=128, BN=128, BK=64; grid (46,79).
// - BN=128: 2x MFMA per staging round vs BN=64; 79*128 = 10112 = VPAD so the
//   boundary tile masks at c4>=4 exactly (10000 = 9984+16).
// - XCD-chunked bijective swizzle; coalesced epilogue (32 lanes = 512B/row
//   segment, bias hoisted -- c4 is constant per thread); tile skip.
// - h_all rows of inactive (t,b) are garbage (attn skipped) -- masked to 0.
// ---------------------------------------------------------------------------
__global__ __launch_bounds__(256) void logits_gemm(
    const unsigned short* __restrict__ A,   // h_all [5888][512]
    const unsigned short* __restrict__ Bm,  // WfcB [10000][512] (+overrun ok)
    const float* __restrict__ bias,         // bfc
    float* __restrict__ out,
    const int* __restrict__ lengths)
{
    constexpr int BM = 128, BN = 128, BK = 64, K = Hc;
    constexpr int EP = 132;  // epilogue fp32 row stride (128 + 4 pad)
    __shared__ __align__(16) unsigned char smraw[BM * EP * 4];  // 67584 B
    unsigned short* sA = (unsigned short*)smraw;                // [128][64] linear
    unsigned short* sB = sA + BM * BK;                          // [128][64] linear
    float* sE = (float*)smraw;

    const int tid = threadIdx.x;
    const int wid = tid >> 6, lane = tid & 63;
    const int wm = wid >> 1, wn = wid & 1;

    // bijective XCD-chunked remap (8 XCDs, grid 46 x 79 = 3634)
    constexpr int NWG = 46 * 79, NX = 8;
    constexpr int qq = NWG / NX, rr = NWG % NX;   // 454, 2
    int wg = blockIdx.x + blockIdx.y * 46;
    int xcd = wg % NX, i = wg / NX;
    int w = (xcd < rr ? xcd * (qq + 1) : rr * (qq + 1) + (xcd - rr) * qq) + i;
    const int m0 = (w % 46) * BM, n0 = (w / 46) * BN;
    constexpr int FM = 4, FN = 4;

    const int c4 = tid & 31;                 // constant per thread
    const int colG = n0 + c4 * 4;
    const bool colOK = colG < Vc;            // Vc%4==0 -> float4 fully in/out

    // ---- inactive-tile fast path ----
    const int tt0 = m0 >> 8;
    if (lengths[m0 & 255] <= tt0) {
        if (colOK) {
            float4 z; z.x = 0.f; z.y = 0.f; z.z = 0.f; z.w = 0.f;
            #pragma unroll
            for (int it = 0; it < 16; it++) {
                int r = it * 8 + (tid >> 5);
                int bb = (m0 + r) & 255;
                *reinterpret_cast<float4*>(
                    out + ((size_t)bb * STEPS + tt0) * Vc + colG) = z;
            }
        }
        return;
    }

    floatx4 acc[FM][FN];
    #pragma unroll
    for (int i2 = 0; i2 < FM; i2++)
        #pragma unroll
        for (int j = 0; j < FN; j++)
            #pragma unroll
            for (int r = 0; r < 4; r++) acc[i2][j][r] = 0.f;

    const int lm = lane & 15, half = lane >> 4;
    const int lane16 = lane * 16;

    for (int k0 = 0; k0 < K; k0 += BK) {
        #pragma unroll
        for (int ii = 0; ii < 4; ii++) {           // A: 16 x 1KB chunks
            int ldso = (wid * 4 + ii) * 1024 + lane16;
            int row = ldso >> 7, colb = ldso & 127;
            int scolb = colb ^ ((row & 7) << 4);
            const char* src = (const char*)(A + (size_t)(m0 + row) * K + k0) + scolb;
            gload_lds16(src, (char*)sA + ldso);
        }
        #pragma unroll
        for (int ii = 0; ii < 4; ii++) {           // B: 16 x 1KB chunks
            int ldso = (wid * 4 + ii) * 1024 + lane16;
            int row = ldso >> 7, colb = ldso & 127;
            int scolb = colb ^ ((row & 7) << 4);
            const char* src = (const char*)(Bm + (size_t)(n0 + row) * K + k0) + scolb;
            gload_lds16(src, (char*)sB + ldso);
        }
        __syncthreads();

        #pragma unroll
        for (int kk = 0; kk < BK; kk += 32) {
            bf16x8 af[FM], bfb[FN];
            #pragma unroll
            for (int fm = 0; fm < FM; fm++) {
                int ar = wm * 64 + fm * 16 + lm;
                int ab = ar * 128 + ((kk * 2 + half * 16) ^ ((ar & 7) << 4));
                af[fm] = *reinterpret_cast<const bf16x8*>((const char*)sA + ab);
            }
            #pragma unroll
            for (int fn = 0; fn < FN; fn++) {
                int br = wn * 64 + fn * 16 + lm;
                int bb = br * 128 + ((kk * 2 + half * 16) ^ ((br & 7) << 4));
                bfb[fn] = *reinterpret_cast<const bf16x8*>((const char*)sB + bb);
            }
            #pragma unroll
            for (int fm = 0; fm < FM; fm++)
                #pragma unroll
                for (int fn = 0; fn < FN; fn++)
                    acc[fm][fn] = __builtin_amdgcn_mfma_f32_16x16x32_bf16(
                        af[fm], bfb[fn], acc[fm][fn], 0, 0, 0);
        }
        __syncthreads();
    }

    // dump acc to LDS fp32 (C-layout)
    const int quad = lane >> 4;
    #pragma unroll
    for (int fm = 0; fm < FM; fm++)
        #pragma unroll
        for (int fn = 0; fn < FN; fn++)
            #pragma unroll
            for (int r = 0; r < 4; r++)
                sE[(wm * 64 + fm * 16 + quad * 4 + r) * EP + wn * 64 + fn * 16 + lm]
                    = acc[fm][fn][r];
    __syncthreads();

    // coalesced epilogue: 32 consecutive lanes cover 512B of one row
    if (colOK) {
        float4 bv = *reinterpret_cast<const float4*>(bias + colG);
        #pragma unroll
        for (int it = 0; it < 16; it++) {
            int r = it * 8 + (tid >> 5);
            int rowG = m0 + r;
            int tt = rowG >> 8, bb = rowG & 255;
            bool act = lengths[bb] > tt;
            float4 v = *reinterpret_cast<const float4*>(sE + r * EP + c4 * 4);
            float4 o;
            o.x = act ? v.x + bv.x : 0.f;
            o.y = act ? v.y + bv.y : 0.f;
            o.z = act ? v.z + bv.z : 0.f;
            o.w = act ? v.w + bv.w : 0.f;
            *reinterpret_cast<float4*>(out + ((size_t)bb * STEPS + tt) * Vc + colG) = o;
        }
    }
}

// ---------------------------------------------------------------------------
// Fused attention + gate-sum + LSTM pointwise. One block per batch row b.
// 1024 threads (16 waves/CU) -- latency-bound loop, confirmed rounds 12-13.
// RAGGED SKIP: inactive rows exit immediately.
// ---------------------------------------------------------------------------
__global__ __launch_bounds__(1024) void attn_lstm_kernel(
    const unsigned short* __restrict__ fproj,    // [256][49][512] bf16
    const unsigned short* __restrict__ fprojG,   // [256][49][2048] bf16
    const unsigned short* __restrict__ embProj,  // [10112][2048] bf16
    const float* __restrict__ hg,                // [256][2560]
    const float* __restrict__ bh,
    const float* __restrict__ Ws,
    const float* __restrict__ bs,
    const float* __restrict__ b_ih,
    const float* __restrict__ b_hh,
    float* __restrict__ c_state,
    unsigned short* __restrict__ h_buf,
    unsigned short* __restrict__ h_all,
    const int* __restrict__ lengths,
    const int* __restrict__ ids,
    int t)
{
    const int b = blockIdx.x, tid = threadIdx.x;
    if (lengths[b] <= t) return;   // ragged skip: h,c preserved; logits masked

    const int wid = tid >> 6, lane = tid & 63;
    __shared__ float s_hp[Acn];
    __shared__ float s_sc[64];
    __shared__ float s_g[2048];

    if (tid < Acn)
        s_hp[tid] = hg[(size_t)b * NG + 2048 + tid] + bh[tid];
    __syncthreads();

    // --- scores: 49 rows over 16 waves (<=4 iters) ---
    float ws8[8], hp8[8];
    {
        const float* wsb = Ws + lane * 8;
        #pragma unroll
        for (int j = 0; j < 8; j++) { ws8[j] = wsb[j]; hp8[j] = s_hp[lane * 8 + j]; }
    }
    for (int r = wid; r < Rc; r += 16) {
        ushort8 e = *reinterpret_cast<const ushort8*>(
            fproj + ((size_t)b * Rc + r) * Acn + lane * 8);
        float sum = 0.f;
        #pragma unroll
        for (int j = 0; j < 8; j++)
            sum += ws8[j] * tanhf(bf2f(e[j]) + hp8[j]);
        #pragma unroll
        for (int off = 32; off > 0; off >>= 1) sum += __shfl_down(sum, off);
        if (lane == 0) s_sc[r] = sum + bs[0];
    }
    __syncthreads();

    // --- softmax over R=49 (wave 0) ---
    if (wid == 0) {
        float v = (lane < Rc) ? s_sc[lane] : -3.0e38f;
        float mx = v;
        #pragma unroll
        for (int off = 32; off > 0; off >>= 1) mx = fmaxf(mx, __shfl_xor(mx, off));
        float e = (lane < Rc) ? __expf(v - mx) : 0.f;
        float sm = e;
        #pragma unroll
        for (int off = 32; off > 0; off >>= 1) sm += __shfl_xor(sm, off);
        if (lane < Rc) s_sc[lane] = e / sm;
    }
    __syncthreads();

    // --- gates: EmbProj[id] + alpha . FprojG + hg + biases (2 per thread) ---
    const int g0 = tid * 2;
    const int id = ids[b * Lc + t];
    float g2[2];
    {
        ushort2v ev = *reinterpret_cast<const ushort2v*>(embProj + (size_t)id * 2048 + g0);
        const float* hgb = hg + (size_t)b * NG + g0;
        #pragma unroll
        for (int j = 0; j < 2; j++)
            g2[j] = bf2f(ev[j]) + hgb[j] + b_ih[g0 + j] + b_hh[g0 + j];
    }
    #pragma unroll 7
    for (int r = 0; r < Rc; r++) {
        float a = s_sc[r];
        ushort2v v = *reinterpret_cast<const ushort2v*>(
            fprojG + ((size_t)b * Rc + r) * 2048 + g0);
        #pragma unroll
        for (int j = 0; j < 2; j++) g2[j] += a * bf2f(v[j]);
    }
    #pragma unroll
    for (int j = 0; j < 2; j++) s_g[g0 + j] = g2[j];
    __syncthreads();

    // --- LSTM pointwise: 1 hidden unit per thread (tid < 512) ---
    if (tid < Hc) {
        int j = tid;
        float gi = s_g[j], gf = s_g[Hc + j], gg = s_g[2 * Hc + j], go = s_g[3 * Hc + j];
        float i_ = 1.f / (1.f + __expf(-gi));
        float f_ = 1.f / (1.f + __expf(-gf));
        float gv = tanhf(gg);
        float o_ = 1.f / (1.f + __expf(-go));
        float c_old = c_state[(size_t)b * Hc + j];
        float ct = f_ * c_old + i_ * gv;
        float ht = o_ * tanhf(ct);
        unsigned short hb = f2bf(ht);
        h_all[((size_t)t * Bc + b) * Hc + j] = hb;
        c_state[(size_t)b * Hc + j] = ct;
        h_buf[(size_t)b * Hc + j] = hb;
    }
}

// ---------------------------------------------------------------------------
// Setup: mean over R of featsB.
// ---------------------------------------------------------------------------
__global__ __launch_bounds__(256) void mean_kernel(
    const unsigned short* __restrict__ featsB,
    unsigned short* __restrict__ meanB)
{
    const int b = blockIdx.x, tid = threadIdx.x;
    const int f0 = tid * 8;
    float s[8];
    #pragma unroll
    for (int j = 0; j < 8; j++) s[j] = 0.f;
    #pragma unroll 7
    for (int r = 0; r < Rc; r++) {
        ushort8 v = *reinterpret_cast<const ushort8*>(
            featsB + ((size_t)(b * Rc + r)) * Fc + f0);
        #pragma unroll
        for (int j = 0; j < 8; j++) s[j] += bf2f(v[j]);
    }
    ushort8 o;
    #pragma unroll
    for (int j = 0; j < 8; j++) o[j] = f2bf(s[j] * (1.f / (float)Rc));
    *reinterpret_cast<ushort8*>(meanB + (size_t)b * Fc + f0) = o;
}

// ---------------------------------------------------------------------------
extern "C" void kernel_launch(void* const* d_in, const int* in_sizes, int n_in,
                              void* d_out, int out_size, void* d_ws, size_t ws_size,
                              hipStream_t stream)
{
    const float* feats = (const float*)d_in[0];
    const int*   ids   = (const int*)d_in[1];
    const int*   lens  = (const int*)d_in[2];
    const float* embW  = (const float*)d_in[3];
    const float* Wf    = (const float*)d_in[4];
    const float* bf_   = (const float*)d_in[5];
    const float* Wh    = (const float*)d_in[6];
    const float* bh    = (const float*)d_in[7];
    const float* Ws_   = (const float*)d_in[8];
    const float* bs_   = (const float*)d_in[9];
    const float* W_ih  = (const float*)d_in[10];
    const float* b_ih  = (const float*)d_in[11];
    const float* W_hh  = (const float*)d_in[12];
    const float* b_hh  = (const float*)d_in[13];
    const float* Wfc   = (const float*)d_in[14];
    const float* bfc   = (const float*)d_in[15];
    const float* Wi_h  = (const float*)d_in[16];
    const float* bi_h  = (const float*)d_in[17];
    const float* Wi_c  = (const float*)d_in[18];
    const float* bi_c  = (const float*)d_in[19];

    char* ws = (char*)d_ws;
    auto alloc_us = [&](size_t n) { unsigned short* p = (unsigned short*)ws; ws += n * 2; return p; };
    auto alloc_f  = [&](size_t n) { float* p = (float*)ws; ws += n * 4; return p; };

    unsigned short* featsB = alloc_us((size_t)Bc * Rc * Fc);
    unsigned short* embB   = alloc_us((size_t)Vc * Ec);
    unsigned short* WfB    = alloc_us((size_t)Acn * Fc);
    unsigned short* WfcB   = alloc_us((size_t)Vc * Hc);
    unsigned short* WihB   = alloc_us((size_t)2048 * XE);
    unsigned short* Whg    = alloc_us((size_t)NG * Hc);   // [W_hh ; Wh]
    unsigned short* WihB2  = alloc_us((size_t)Hc * Fc);   // Wi_h
    unsigned short* WicB   = alloc_us((size_t)Hc * Fc);   // Wi_c
    unsigned short* meanB  = alloc_us((size_t)Bc * Fc);
    unsigned short* fproj  = alloc_us((size_t)Bc * Rc * Acn);
    unsigned short* fprojG = alloc_us((size_t)Bc * Rc * 2048);   // feats @ W_ctx^T
    unsigned short* embPrj = alloc_us((size_t)VPAD * 2048);      // embW @ W_emb^T (padded rows)
    unsigned short* h_buf  = alloc_us((size_t)Bc * Hc);
    unsigned short* h_all  = alloc_us((size_t)STEPS * Bc * Hc);
    float*          c_st   = alloc_f((size_t)Bc * Hc);
    float*          hg     = alloc_f((size_t)Bc * NG);
    float*          outF   = (float*)d_out;

    CvtArgs ca;
    ca.src[0] = feats; ca.dst[0] = featsB;
    ca.src[1] = embW;  ca.dst[1] = embB;
    ca.src[2] = Wf;    ca.dst[2] = WfB;
    ca.src[3] = Wfc;   ca.dst[3] = WfcB;
    ca.src[4] = W_ih;  ca.dst[4] = WihB;
    ca.src[5] = W_hh;  ca.dst[5] = Whg;                       // rows 0..2047
    ca.src[6] = Wh;    ca.dst[6] = Whg + (size_t)2048 * Hc;   // rows 2048..2559
    ca.src[7] = Wi_h;  ca.dst[7] = WihB2;
    ca.src[8] = Wi_c;  ca.dst[8] = WicB;
    convert_all<<<CVT_BLOCKS, 256, 0, stream>>>(ca);

    mean_kernel<<<Bc, 256, 0, stream>>>(featsB, meanB);

    // h0/c0 init: M=256, N=1024 (Wi_h|Wi_c), K=2048, tanh epilogue
    gemm_tn<64, 64, 64, 2><<<dim3(4, 16), 256, 0, stream>>>(
        meanB, Fc, WihB2, Fc, WicB, bi_h, bi_c,
        nullptr, h_buf, c_st, 2 * Hc, Fc, nullptr, 0);

    // f_proj: M=12544, N=512, K=2048 -> bf16 (n-fastest dispatch: A once)
    gemm_tn<128, 128, 64, 1, true><<<dim3(4, 98), 256, 0, stream>>>(
        featsB, Fc, WfB, Fc, nullptr, bf_, nullptr,
        nullptr, fproj, nullptr, Acn, Fc, nullptr, 0);

    // FprojG = feats @ W_ih[:,256:]^T : M=12544, N=2048, K=2048 -> bf16
    gemm_tn<128, 128, 64, 1, true><<<dim3(16, 98), 256, 0, stream>>>(
        featsB, Fc, WihB + 256, XE, nullptr, nullptr, nullptr,
        nullptr, fprojG, nullptr, 2048, Fc, nullptr, 0);

    // EmbProj = embW @ W_ih[:,0:256]^T : M=10112 (padded), N=2048, K=256 -> bf16
    gemm_tn<128, 128, 64, 1, true><<<dim3(16, VPAD / 128), 256, 0, stream>>>(
        embB, Ec, WihB, XE, nullptr, nullptr, nullptr,
        nullptr, embPrj, nullptr, 2048, Ec, nullptr, 0);

    for (int t = 0; t < STEPS; t++) {
        // hgemm: hg = h @ [W_hh;Wh]^T : M=256, N=2560, K=512.
        // BK=256 -> 2 staging/barrier rounds instead of 8 (loop is latency-
        // bound; K-accumulation order unchanged -> bit-identical).
        // LDS 48KB -> 3 blocks/CU; 320 blocks all resident.
        gemm_tn<64, 32, 256, 0><<<dim3(4, 80), 256, 0, stream>>>(
            h_buf, Hc, Whg, Hc, nullptr, nullptr, nullptr,
            hg, nullptr, nullptr, NG, Hc, lens, t);

        // fused attention + gate-sum + LSTM pointwise (1024 thr, ragged skip)
        attn_lstm_kernel<<<Bc, 1024, 0, stream>>>(
            fproj, fprojG, embPrj, hg, bh, Ws_, bs_, b_ih, b_hh,
            c_st, h_buf, h_all, lens, ids, t);
    }

    // batched logits: M=5888, N=10000 (tiled to 10112), K=512
    logits_gemm<<<dim3(46, 79), 256, 0, stream>>>(
        h_all, WfcB, bfc, outF, lens);
}